// Round 1
// baseline (457.341 us; speedup 1.0000x reference)
//
#include <hip/hip_runtime.h>
#include <math.h>

#define B_   8
#define C_   256
#define HW_  4096
#define BM   64
#define BN   64
#define BK   16
#define LDT  68      // padded LDS tile row stride (68*4B = 272B, 16B-aligned rows, 2-way-max bank alias)
#define KSPLIT 4
#define KCH  (HW_ / KSPLIT)   // 1024

// ---------------------------------------------------------------------------
// GEMM: Y[b][m][n] = sum_k A[b][m][k] * X[b][k][n] + bias[m]
// A row-major [M,K] (reduction contiguous), X [K,N] (n contiguous).
// Tiles 64x64x16; block 256 threads, 4x4 micro-tile per thread.
// ---------------------------------------------------------------------------
__global__ __launch_bounds__(256) void gemm_wx(
    const float* __restrict__ A, long strideA,
    const float* __restrict__ X, long strideX,
    const float* __restrict__ bias,
    float* __restrict__ Y, long strideY,
    int M, int N, int K)
{
    __shared__ float As[BK][LDT];   // transposed: As[k][m]
    __shared__ float Xs[BK][LDT];   // natural:   Xs[k][n]

    const int b  = blockIdx.z;
    const int m0 = blockIdx.y * BM;
    const int n0 = blockIdx.x * BN;
    const float* Ab = A + (long)b * strideA;
    const float* Xb = X + (long)b * strideX;
    float*       Yb = Y + (long)b * strideY;

    const int t   = threadIdx.x;
    const int tx  = t & 15, ty = t >> 4;
    const int tx4 = tx * 4, ty4 = ty * 4;
    // A-tile load mapping: row am (0..63), 4 contiguous k at ak4
    const int am  = t >> 2, ak4 = (t & 3) * 4;
    // X-tile load mapping: row xk (0..15), 4 contiguous n at xn4
    const int xk  = ty,     xn4 = tx4;

    float acc[4][4] = {};

    for (int k0 = 0; k0 < K; k0 += BK) {
        float4 av = *reinterpret_cast<const float4*>(&Ab[(long)(m0 + am) * K + k0 + ak4]);
        float4 xv = *reinterpret_cast<const float4*>(&Xb[(long)(k0 + xk) * N + n0 + xn4]);
        As[ak4 + 0][am] = av.x;
        As[ak4 + 1][am] = av.y;
        As[ak4 + 2][am] = av.z;
        As[ak4 + 3][am] = av.w;
        *reinterpret_cast<float4*>(&Xs[xk][xn4]) = xv;
        __syncthreads();
        #pragma unroll
        for (int kk = 0; kk < BK; ++kk) {
            float4 a = *reinterpret_cast<const float4*>(&As[kk][ty4]);
            float4 x = *reinterpret_cast<const float4*>(&Xs[kk][tx4]);
            float ar[4] = {a.x, a.y, a.z, a.w};
            float xr[4] = {x.x, x.y, x.z, x.w};
            #pragma unroll
            for (int r = 0; r < 4; ++r)
                #pragma unroll
                for (int s = 0; s < 4; ++s)
                    acc[r][s] = fmaf(ar[r], xr[s], acc[r][s]);
        }
        __syncthreads();
    }

    #pragma unroll
    for (int r = 0; r < 4; ++r) {
        const int m = m0 + ty4 + r;
        const float bv = bias ? bias[m] : 0.0f;
        float4 o;
        o.x = acc[r][0] + bv;
        o.y = acc[r][1] + bv;
        o.z = acc[r][2] + bv;
        o.w = acc[r][3] + bv;
        *reinterpret_cast<float4*>(&Yb[(long)m * N + n0 + tx4]) = o;
    }
}

// ---------------------------------------------------------------------------
// NT GEMM with K-split: part[z][c][d] = sum_{i in chunk} Q[b][c][i]*Km[b][d][i]
// z = b*KSPLIT + ks. Both operands have reduction (i) contiguous.
// ---------------------------------------------------------------------------
__global__ __launch_bounds__(256) void gemm_nt(
    const float* __restrict__ Q,
    const float* __restrict__ Km,
    float* __restrict__ part)
{
    __shared__ float As[BK][LDT];   // As[i][c]
    __shared__ float Bs[BK][LDT];   // Bs[i][d]

    const int z  = blockIdx.z;           // b*KSPLIT + ks
    const int b  = z >> 2;
    const int ks = z & (KSPLIT - 1);
    const int c0 = blockIdx.y * BM;
    const int d0 = blockIdx.x * BN;
    const float* Qb = Q  + (long)b * C_ * HW_;
    const float* Kb = Km + (long)b * C_ * HW_;

    const int t   = threadIdx.x;
    const int tx  = t & 15, ty = t >> 4;
    const int tx4 = tx * 4, ty4 = ty * 4;
    const int am  = t >> 2, ak4 = (t & 3) * 4;

    float acc[4][4] = {};
    const int i0 = ks * KCH;

    for (int kt = 0; kt < KCH; kt += BK) {
        float4 qv = *reinterpret_cast<const float4*>(&Qb[(long)(c0 + am) * HW_ + i0 + kt + ak4]);
        float4 kv = *reinterpret_cast<const float4*>(&Kb[(long)(d0 + am) * HW_ + i0 + kt + ak4]);
        As[ak4 + 0][am] = qv.x;
        As[ak4 + 1][am] = qv.y;
        As[ak4 + 2][am] = qv.z;
        As[ak4 + 3][am] = qv.w;
        Bs[ak4 + 0][am] = kv.x;
        Bs[ak4 + 1][am] = kv.y;
        Bs[ak4 + 2][am] = kv.z;
        Bs[ak4 + 3][am] = kv.w;
        __syncthreads();
        #pragma unroll
        for (int kk = 0; kk < BK; ++kk) {
            float4 a = *reinterpret_cast<const float4*>(&As[kk][ty4]);
            float4 x = *reinterpret_cast<const float4*>(&Bs[kk][tx4]);
            float ar[4] = {a.x, a.y, a.z, a.w};
            float xr[4] = {x.x, x.y, x.z, x.w};
            #pragma unroll
            for (int r = 0; r < 4; ++r)
                #pragma unroll
                for (int s = 0; s < 4; ++s)
                    acc[r][s] = fmaf(ar[r], xr[s], acc[r][s]);
        }
        __syncthreads();
    }

    float* P = part + (long)z * C_ * C_;
    #pragma unroll
    for (int r = 0; r < 4; ++r) {
        float4 o;
        o.x = acc[r][0]; o.y = acc[r][1]; o.z = acc[r][2]; o.w = acc[r][3];
        *reinterpret_cast<float4*>(&P[(long)(c0 + ty4 + r) * C_ + d0 + tx4]) = o;
    }
}

// corr[b][e] = sum_ks part[b*KSPLIT+ks][e],  e in [0, C*C)
__global__ __launch_bounds__(256) void reduce_part(
    const float* __restrict__ part, float* __restrict__ corr)
{
    const long idx = (long)blockIdx.x * 256 + threadIdx.x;   // over B*C*C
    const int  b   = (int)(idx >> 16);                       // C*C = 65536
    const long e   = idx & 65535;
    const float* p = part + (long)b * KSPLIT * 65536 + e;
    corr[idx] = p[0] + p[65536] + p[2 * 65536] + p[3 * 65536];
}

// One block per (b,c) row: stats[row] = max, stats[B*C + row] = sum(exp(s-max))
__global__ __launch_bounds__(256) void softmax_stats(
    const float* __restrict__ S, float* __restrict__ stats)
{
    const int row = blockIdx.x;
    const float* sr = S + (long)row * HW_;
    const int t = threadIdx.x;

    float4 x[4];
    #pragma unroll
    for (int j = 0; j < 4; ++j)
        x[j] = *reinterpret_cast<const float4*>(&sr[(j * 256 + t) * 4]);

    float m = -INFINITY;
    #pragma unroll
    for (int j = 0; j < 4; ++j) {
        m = fmaxf(m, fmaxf(fmaxf(x[j].x, x[j].y), fmaxf(x[j].z, x[j].w)));
    }
    __shared__ float red[8];
    #pragma unroll
    for (int o = 32; o > 0; o >>= 1) m = fmaxf(m, __shfl_xor(m, o));
    const int wid = t >> 6;
    if ((t & 63) == 0) red[wid] = m;
    __syncthreads();
    m = fmaxf(fmaxf(red[0], red[1]), fmaxf(red[2], red[3]));

    float sum = 0.0f;
    #pragma unroll
    for (int j = 0; j < 4; ++j) {
        sum += __expf(x[j].x - m) + __expf(x[j].y - m)
             + __expf(x[j].z - m) + __expf(x[j].w - m);
    }
    #pragma unroll
    for (int o = 32; o > 0; o >>= 1) sum += __shfl_xor(sum, o);
    if ((t & 63) == 0) red[4 + wid] = sum;
    __syncthreads();
    if (t == 0) {
        stats[row]            = m;
        stats[B_ * C_ + row]  = red[4] + red[5] + red[6] + red[7];
    }
}

// out = fg*mask + gamma*(1-mask)*softmax(s)*v   (elementwise, float4)
__global__ __launch_bounds__(256) void finalize(
    const float* __restrict__ fg, const float* __restrict__ mask,
    const float* __restrict__ S,  const float* __restrict__ V,
    const float* __restrict__ stats, const float* __restrict__ gamma,
    float* __restrict__ out)
{
    const long i4  = (long)blockIdx.x * 256 + threadIdx.x;   // float4 index
    const int  row = (int)(i4 >> 10);                        // / (HW/4)
    const float m   = stats[row];
    const float inv = 1.0f / stats[B_ * C_ + row];
    const float g   = gamma[0];
    const long e = i4 * 4;

    float4 f  = *reinterpret_cast<const float4*>(fg   + e);
    float4 mk = *reinterpret_cast<const float4*>(mask + e);
    float4 sv = *reinterpret_cast<const float4*>(S    + e);
    float4 vv = *reinterpret_cast<const float4*>(V    + e);

    float4 o;
    o.x = f.x * mk.x + g * (1.0f - mk.x) * (__expf(sv.x - m) * inv) * vv.x;
    o.y = f.y * mk.y + g * (1.0f - mk.y) * (__expf(sv.y - m) * inv) * vv.y;
    o.z = f.z * mk.z + g * (1.0f - mk.z) * (__expf(sv.z - m) * inv) * vv.z;
    o.w = f.w * mk.w + g * (1.0f - mk.w) * (__expf(sv.w - m) * inv) * vv.w;
    *reinterpret_cast<float4*>(out + e) = o;
}

// ---------------------------------------------------------------------------
extern "C" void kernel_launch(void* const* d_in, const int* in_sizes, int n_in,
                              void* d_out, int out_size, void* d_ws, size_t ws_size,
                              hipStream_t stream)
{
    const float* fg    = (const float*)d_in[0];
    const float* bg    = (const float*)d_in[1];
    const float* mask  = (const float*)d_in[2];
    const float* Wq    = (const float*)d_in[3];
    const float* bq    = (const float*)d_in[4];
    const float* Wk    = (const float*)d_in[5];
    const float* bk    = (const float*)d_in[6];
    const float* Wv    = (const float*)d_in[7];
    const float* bv    = (const float*)d_in[8];
    const float* gamma = (const float*)d_in[9];
    float* out = (float*)d_out;

    // workspace layout (floats)
    float* ws    = (float*)d_ws;
    float* q     = ws;                              // B*C*HW = 8388608 (later reused for scores)
    float* kv    = ws + 8388608;                    // k, later v
    float* part  = ws + 2 * 8388608;                // KSPLIT*B*C*C = 2097152
    float* corr  = part + KSPLIT * B_ * C_ * C_;    // B*C*C = 524288
    float* stats = corr + B_ * C_ * C_;             // 2*B*C = 4096
    float* scores = q;

    const long sCHW = (long)C_ * HW_;
    const dim3 blk(256);
    const dim3 gWX(HW_ / BN, C_ / BM, B_);          // (64,4,8)

    // q = Wq*fg + bq ; k = Wk*bg + bk
    gemm_wx<<<gWX, blk, 0, stream>>>(Wq, 0, fg, sCHW, bq, q,  sCHW, C_, HW_, C_);
    gemm_wx<<<gWX, blk, 0, stream>>>(Wk, 0, bg, sCHW, bk, kv, sCHW, C_, HW_, C_);

    // corr partials (K-split over HW) then reduce
    const dim3 gNT(C_ / BN, C_ / BM, B_ * KSPLIT);  // (4,4,32)
    gemm_nt<<<gNT, blk, 0, stream>>>(q, kv, part);
    reduce_part<<<dim3(B_ * C_ * C_ / 256), blk, 0, stream>>>(part, corr);

    // v = Wv*fg + bv  (overwrites k buffer; k is dead)
    gemm_wx<<<gWX, blk, 0, stream>>>(Wv, 0, fg, sCHW, bv, kv, sCHW, C_, HW_, C_);

    // scores = corr * mask (overwrites q buffer; q is dead)
    gemm_wx<<<gWX, blk, 0, stream>>>(corr, (long)C_ * C_, mask, sCHW, nullptr,
                                     scores, sCHW, C_, HW_, C_);

    // softmax stats per row, then fused elementwise epilogue
    softmax_stats<<<dim3(B_ * C_), blk, 0, stream>>>(scores, stats);
    finalize<<<dim3(B_ * C_ * HW_ / 4 / 256), blk, 0, stream>>>(
        fg, mask, scores, kv, stats, gamma, out);
}

// Round 2
// 392.337 us; speedup vs baseline: 1.1657x; 1.1657x over previous
//
#include <hip/hip_runtime.h>
#include <math.h>

#define B_    8
#define C_    256
#define HW_   4096
#define CHW_  ((long)C_ * HW_)

// ---- 128x128 tile config (big GEMMs) ----
#define BK    16
#define LDT   132     // padded LDS row stride (132*4B = 528B = 33*16B -> b128-aligned rows)
#define KS    32      // K-split for the NT (F·G^T) GEMM
#define KCH   (HW_ / KS)   // 128

// ---- 64x64 tile config (small GEMMs) ----
#define LDT64 68

// ===========================================================================
// NT GEMM, 128x128 tile, 8x8 micro: part[z][c][d] = sum_{i in chunk} F[b][c][i]*G[b][d][i]
// z = b*KS + ks. Both operands K-contiguous.
// ===========================================================================
__global__ __launch_bounds__(256, 4) void gemm_nt128(
    const float* __restrict__ F, const float* __restrict__ G,
    float* __restrict__ part)
{
    __shared__ float As[BK][LDT];
    __shared__ float Bs[BK][LDT];

    const int z  = blockIdx.z;
    const int b  = z >> 5;
    const int ks = z & (KS - 1);
    const int c0 = blockIdx.y * 128;
    const int d0 = blockIdx.x * 128;
    const int i0 = ks * KCH;
    const float* Fb = F + (long)b * CHW_;
    const float* Gb = G + (long)b * CHW_;

    const int t    = threadIdx.x;
    const int tx   = t & 15, ty = t >> 4;
    const int tx4  = tx * 4, ty4 = ty * 4;
    const int arow = t >> 1;             // 0..127
    const int ak   = (t & 1) * 8;        // 0 or 8

    float acc[8][8] = {};

    for (int kt = 0; kt < KCH; kt += BK) {
        const long ai = (long)(c0 + arow) * HW_ + i0 + kt + ak;
        const long bi = (long)(d0 + arow) * HW_ + i0 + kt + ak;
        float4 a0 = *reinterpret_cast<const float4*>(&Fb[ai]);
        float4 a1 = *reinterpret_cast<const float4*>(&Fb[ai + 4]);
        float4 g0 = *reinterpret_cast<const float4*>(&Gb[bi]);
        float4 g1 = *reinterpret_cast<const float4*>(&Gb[bi + 4]);
        As[ak+0][arow]=a0.x; As[ak+1][arow]=a0.y; As[ak+2][arow]=a0.z; As[ak+3][arow]=a0.w;
        As[ak+4][arow]=a1.x; As[ak+5][arow]=a1.y; As[ak+6][arow]=a1.z; As[ak+7][arow]=a1.w;
        Bs[ak+0][arow]=g0.x; Bs[ak+1][arow]=g0.y; Bs[ak+2][arow]=g0.z; Bs[ak+3][arow]=g0.w;
        Bs[ak+4][arow]=g1.x; Bs[ak+5][arow]=g1.y; Bs[ak+6][arow]=g1.z; Bs[ak+7][arow]=g1.w;
        __syncthreads();
        #pragma unroll
        for (int kk = 0; kk < BK; ++kk) {
            float4 a0f = *reinterpret_cast<const float4*>(&As[kk][ty4]);
            float4 a1f = *reinterpret_cast<const float4*>(&As[kk][ty4 + 64]);
            float4 b0f = *reinterpret_cast<const float4*>(&Bs[kk][tx4]);
            float4 b1f = *reinterpret_cast<const float4*>(&Bs[kk][tx4 + 64]);
            const float ar[8] = {a0f.x,a0f.y,a0f.z,a0f.w,a1f.x,a1f.y,a1f.z,a1f.w};
            const float br[8] = {b0f.x,b0f.y,b0f.z,b0f.w,b1f.x,b1f.y,b1f.z,b1f.w};
            #pragma unroll
            for (int i = 0; i < 8; ++i)
                #pragma unroll
                for (int j = 0; j < 8; ++j)
                    acc[i][j] = fmaf(ar[i], br[j], acc[i][j]);
        }
        __syncthreads();
    }

    float* P = part + (long)z * C_ * C_;
    #pragma unroll
    for (int i = 0; i < 8; ++i) {
        const int r = c0 + (i >> 2) * 64 + ty4 + (i & 3);
        float4 o0, o1;
        o0.x = acc[i][0]; o0.y = acc[i][1]; o0.z = acc[i][2]; o0.w = acc[i][3];
        o1.x = acc[i][4]; o1.y = acc[i][5]; o1.z = acc[i][6]; o1.w = acc[i][7];
        *reinterpret_cast<float4*>(&P[(long)r * C_ + d0 + tx4])      = o0;
        *reinterpret_cast<float4*>(&P[(long)r * C_ + d0 + 64 + tx4]) = o1;
    }
}

// ===========================================================================
// NN GEMM, 128x128 tile, 8x8 micro: Y[b] = A[b] * X[b]  (A K-contig, X n-contig)
// Used for scores = corr * mask.
// ===========================================================================
__global__ __launch_bounds__(256, 4) void gemm_nn128(
    const float* __restrict__ A, long strideA,
    const float* __restrict__ X, long strideX,
    float* __restrict__ Y, long strideY,
    int N, int K)
{
    __shared__ float As[BK][LDT];
    __shared__ float Bs[BK][LDT];

    const int b  = blockIdx.z;
    const int m0 = blockIdx.y * 128;
    const int n0 = blockIdx.x * 128;
    const float* Ab = A + (long)b * strideA;
    const float* Xb = X + (long)b * strideX;
    float*       Yb = Y + (long)b * strideY;

    const int t    = threadIdx.x;
    const int tx   = t & 15, ty = t >> 4;
    const int tx4  = tx * 4, ty4 = ty * 4;
    const int arow = t >> 1;
    const int ak   = (t & 1) * 8;
    const int xk   = t >> 4;             // 0..15
    const int xn   = (t & 15) * 8;

    float acc[8][8] = {};

    for (int k0 = 0; k0 < K; k0 += BK) {
        const long ai = (long)(m0 + arow) * K + k0 + ak;
        float4 a0 = *reinterpret_cast<const float4*>(&Ab[ai]);
        float4 a1 = *reinterpret_cast<const float4*>(&Ab[ai + 4]);
        const long xi = (long)(k0 + xk) * N + n0 + xn;
        float4 x0 = *reinterpret_cast<const float4*>(&Xb[xi]);
        float4 x1 = *reinterpret_cast<const float4*>(&Xb[xi + 4]);
        As[ak+0][arow]=a0.x; As[ak+1][arow]=a0.y; As[ak+2][arow]=a0.z; As[ak+3][arow]=a0.w;
        As[ak+4][arow]=a1.x; As[ak+5][arow]=a1.y; As[ak+6][arow]=a1.z; As[ak+7][arow]=a1.w;
        *reinterpret_cast<float4*>(&Bs[xk][xn])     = x0;
        *reinterpret_cast<float4*>(&Bs[xk][xn + 4]) = x1;
        __syncthreads();
        #pragma unroll
        for (int kk = 0; kk < BK; ++kk) {
            float4 a0f = *reinterpret_cast<const float4*>(&As[kk][ty4]);
            float4 a1f = *reinterpret_cast<const float4*>(&As[kk][ty4 + 64]);
            float4 b0f = *reinterpret_cast<const float4*>(&Bs[kk][tx4]);
            float4 b1f = *reinterpret_cast<const float4*>(&Bs[kk][tx4 + 64]);
            const float ar[8] = {a0f.x,a0f.y,a0f.z,a0f.w,a1f.x,a1f.y,a1f.z,a1f.w};
            const float br[8] = {b0f.x,b0f.y,b0f.z,b0f.w,b1f.x,b1f.y,b1f.z,b1f.w};
            #pragma unroll
            for (int i = 0; i < 8; ++i)
                #pragma unroll
                for (int j = 0; j < 8; ++j)
                    acc[i][j] = fmaf(ar[i], br[j], acc[i][j]);
        }
        __syncthreads();
    }

    #pragma unroll
    for (int i = 0; i < 8; ++i) {
        const int m = m0 + (i >> 2) * 64 + ty4 + (i & 3);
        float4 o0, o1;
        o0.x = acc[i][0]; o0.y = acc[i][1]; o0.z = acc[i][2]; o0.w = acc[i][3];
        o1.x = acc[i][4]; o1.y = acc[i][5]; o1.z = acc[i][6]; o1.w = acc[i][7];
        *reinterpret_cast<float4*>(&Yb[(long)m * N + n0 + tx4])      = o0;
        *reinterpret_cast<float4*>(&Yb[(long)m * N + n0 + 64 + tx4]) = o1;
    }
}

// ===========================================================================
// v = Wv*fg + bv, fused with finalize epilogue:
// out = fg*mask + gamma*(1-mask)*exp(scores-m)*inv*v
// ===========================================================================
__global__ __launch_bounds__(256, 4) void gemm_v_final128(
    const float* __restrict__ Wv, const float* __restrict__ fg,
    const float* __restrict__ bv, const float* __restrict__ mask,
    const float* __restrict__ S,  const float* __restrict__ stats,
    const float* __restrict__ gamma, float* __restrict__ out)
{
    __shared__ float As[BK][LDT];
    __shared__ float Bs[BK][LDT];

    const int b  = blockIdx.z;
    const int m0 = blockIdx.y * 128;
    const int n0 = blockIdx.x * 128;
    const float* Xb = fg + (long)b * CHW_;

    const int t    = threadIdx.x;
    const int tx   = t & 15, ty = t >> 4;
    const int tx4  = tx * 4, ty4 = ty * 4;
    const int arow = t >> 1;
    const int ak   = (t & 1) * 8;
    const int xk   = t >> 4;
    const int xn   = (t & 15) * 8;

    float acc[8][8] = {};

    for (int k0 = 0; k0 < C_; k0 += BK) {
        const long ai = (long)(m0 + arow) * C_ + k0 + ak;
        float4 a0 = *reinterpret_cast<const float4*>(&Wv[ai]);
        float4 a1 = *reinterpret_cast<const float4*>(&Wv[ai + 4]);
        const long xi = (long)(k0 + xk) * HW_ + n0 + xn;
        float4 x0 = *reinterpret_cast<const float4*>(&Xb[xi]);
        float4 x1 = *reinterpret_cast<const float4*>(&Xb[xi + 4]);
        As[ak+0][arow]=a0.x; As[ak+1][arow]=a0.y; As[ak+2][arow]=a0.z; As[ak+3][arow]=a0.w;
        As[ak+4][arow]=a1.x; As[ak+5][arow]=a1.y; As[ak+6][arow]=a1.z; As[ak+7][arow]=a1.w;
        *reinterpret_cast<float4*>(&Bs[xk][xn])     = x0;
        *reinterpret_cast<float4*>(&Bs[xk][xn + 4]) = x1;
        __syncthreads();
        #pragma unroll
        for (int kk = 0; kk < BK; ++kk) {
            float4 a0f = *reinterpret_cast<const float4*>(&As[kk][ty4]);
            float4 a1f = *reinterpret_cast<const float4*>(&As[kk][ty4 + 64]);
            float4 b0f = *reinterpret_cast<const float4*>(&Bs[kk][tx4]);
            float4 b1f = *reinterpret_cast<const float4*>(&Bs[kk][tx4 + 64]);
            const float ar[8] = {a0f.x,a0f.y,a0f.z,a0f.w,a1f.x,a1f.y,a1f.z,a1f.w};
            const float br[8] = {b0f.x,b0f.y,b0f.z,b0f.w,b1f.x,b1f.y,b1f.z,b1f.w};
            #pragma unroll
            for (int i = 0; i < 8; ++i)
                #pragma unroll
                for (int j = 0; j < 8; ++j)
                    acc[i][j] = fmaf(ar[i], br[j], acc[i][j]);
        }
        __syncthreads();
    }

    const float g = gamma[0];
    #pragma unroll
    for (int i = 0; i < 8; ++i) {
        const int m   = m0 + (i >> 2) * 64 + ty4 + (i & 3);
        const int row = b * C_ + m;
        const float mx  = stats[row];
        const float inv = 1.0f / stats[2048 + row];
        const float bvm = bv[m];
        #pragma unroll
        for (int si = 0; si < 2; ++si) {
            const int n = n0 + si * 64 + tx4;
            const long e = (long)b * CHW_ + (long)m * HW_ + n;
            float4 f  = *reinterpret_cast<const float4*>(&fg[e]);
            float4 mk = *reinterpret_cast<const float4*>(&mask[e]);
            float4 sv = *reinterpret_cast<const float4*>(&S[e]);
            float4 o;
            const float v0 = acc[i][si*4+0] + bvm;
            const float v1 = acc[i][si*4+1] + bvm;
            const float v2 = acc[i][si*4+2] + bvm;
            const float v3 = acc[i][si*4+3] + bvm;
            o.x = f.x*mk.x + g*(1.0f-mk.x)*(__expf(sv.x-mx)*inv)*v0;
            o.y = f.y*mk.y + g*(1.0f-mk.y)*(__expf(sv.y-mx)*inv)*v1;
            o.z = f.z*mk.z + g*(1.0f-mk.z)*(__expf(sv.z-mx)*inv)*v2;
            o.w = f.w*mk.w + g*(1.0f-mk.w)*(__expf(sv.w-mx)*inv)*v3;
            *reinterpret_cast<float4*>(&out[e]) = o;
        }
    }
}

// ===========================================================================
// rowsums: fsum[b*C+c] = sum_i fg[b][c][i];  gsum similarly for bg.
// ===========================================================================
__global__ __launch_bounds__(256) void rowsums(
    const float* __restrict__ fg, const float* __restrict__ bg,
    float* __restrict__ fsum, float* __restrict__ gsum)
{
    const int row = blockIdx.x;            // 0..2047
    const int t   = threadIdx.x;
    const float* fr = fg + (long)row * HW_;
    const float* gr = bg + (long)row * HW_;

    float sf = 0.0f, sg = 0.0f;
    #pragma unroll
    for (int j = 0; j < 4; ++j) {
        float4 a = *reinterpret_cast<const float4*>(&fr[(j * 256 + t) * 4]);
        float4 c = *reinterpret_cast<const float4*>(&gr[(j * 256 + t) * 4]);
        sf += a.x + a.y + a.z + a.w;
        sg += c.x + c.y + c.z + c.w;
    }
    #pragma unroll
    for (int o = 32; o > 0; o >>= 1) { sf += __shfl_xor(sf, o); sg += __shfl_xor(sg, o); }
    __shared__ float red[8];
    const int wid = t >> 6;
    if ((t & 63) == 0) { red[wid] = sf; red[4 + wid] = sg; }
    __syncthreads();
    if (t == 0) {
        fsum[row] = red[0] + red[1] + red[2] + red[3];
        gsum[row] = red[4] + red[5] + red[6] + red[7];
    }
}

// S1[b*65536+e] = sum_{ks<32} part[(b*32+ks)*65536 + e]
__global__ __launch_bounds__(256) void reduce_part(
    const float* __restrict__ part, float* __restrict__ S1)
{
    const long idx = (long)blockIdx.x * 256 + threadIdx.x;   // over B*C*C = 524288
    const int  b   = (int)(idx >> 16);
    const long e   = idx & 65535;
    const float* p = part + ((long)b << 5) * 65536 + e;
    float s = 0.0f;
    #pragma unroll
    for (int ks = 0; ks < KS; ++ks) s += p[(long)ks * 65536];
    S1[idx] = s;
}

// u[b*C+c] = sum_e Wq[c][e]*fsum[b][e]; wh[b*C+d] = sum_f Wk[d][f]*gsum[b][f] + HW*bk[d]
__global__ __launch_bounds__(256) void uvw_kernel(
    const float* __restrict__ Wq, const float* __restrict__ Wk,
    const float* __restrict__ bk,
    const float* __restrict__ fsum, const float* __restrict__ gsum,
    float* __restrict__ u, float* __restrict__ wh)
{
    const int g = blockIdx.x * 256 + threadIdx.x;   // 0..4095
    if (g < 2048) {
        const int b = g >> 8, c = g & 255;
        const float* w = Wq + (long)c * C_;
        const float* s = fsum + b * C_;
        float acc = 0.0f;
        for (int e = 0; e < C_; ++e) acc = fmaf(w[e], s[e], acc);
        u[g] = acc;
    } else {
        const int g2 = g - 2048;
        const int b = g2 >> 8, d = g2 & 255;
        const float* w = Wk + (long)d * C_;
        const float* s = gsum + b * C_;
        float acc = 0.0f;
        for (int f = 0; f < C_; ++f) acc = fmaf(w[f], s[f], acc);
        wh[g2] = acc + (float)HW_ * bk[d];
    }
}

// ===========================================================================
// Small NT GEMM 64x64/4x4: T[r][d] = sum_f S1[r][f] * Wk[d][f]
// M=2048 (rows r = b*C+e), N=256, K=256.
// ===========================================================================
__global__ __launch_bounds__(256) void gemm_nt64(
    const float* __restrict__ S1, const float* __restrict__ Wk,
    float* __restrict__ T)
{
    __shared__ float As[BK][LDT64];
    __shared__ float Bs[BK][LDT64];

    const int r0 = blockIdx.y * 64;
    const int d0 = blockIdx.x * 64;
    const int t   = threadIdx.x;
    const int tx  = t & 15, ty = t >> 4;
    const int tx4 = tx * 4, ty4 = ty * 4;
    const int am  = t >> 2, ak4 = (t & 3) * 4;

    float acc[4][4] = {};
    for (int k0 = 0; k0 < C_; k0 += BK) {
        float4 av = *reinterpret_cast<const float4*>(&S1[(long)(r0 + am) * C_ + k0 + ak4]);
        float4 bw = *reinterpret_cast<const float4*>(&Wk[(long)(d0 + am) * C_ + k0 + ak4]);
        As[ak4+0][am]=av.x; As[ak4+1][am]=av.y; As[ak4+2][am]=av.z; As[ak4+3][am]=av.w;
        Bs[ak4+0][am]=bw.x; Bs[ak4+1][am]=bw.y; Bs[ak4+2][am]=bw.z; Bs[ak4+3][am]=bw.w;
        __syncthreads();
        #pragma unroll
        for (int kk = 0; kk < BK; ++kk) {
            float4 a = *reinterpret_cast<const float4*>(&As[kk][ty4]);
            float4 x = *reinterpret_cast<const float4*>(&Bs[kk][tx4]);
            const float ar[4] = {a.x,a.y,a.z,a.w};
            const float xr[4] = {x.x,x.y,x.z,x.w};
            #pragma unroll
            for (int r = 0; r < 4; ++r)
                #pragma unroll
                for (int s = 0; s < 4; ++s)
                    acc[r][s] = fmaf(ar[r], xr[s], acc[r][s]);
        }
        __syncthreads();
    }
    #pragma unroll
    for (int r = 0; r < 4; ++r) {
        float4 o; o.x=acc[r][0]; o.y=acc[r][1]; o.z=acc[r][2]; o.w=acc[r][3];
        *reinterpret_cast<float4*>(&T[(long)(r0 + ty4 + r) * C_ + d0 + tx4]) = o;
    }
}

// ===========================================================================
// Small NN GEMM 64x64/4x4 + rank-1 epilogue:
// corr[b][c][d] = sum_e Wq[c][e]*T[b][e][d] + u[b*C+c]*bk[d] + bq[c]*wh[b*C+d]
// ===========================================================================
__global__ __launch_bounds__(256) void gemm_nn64_rank1(
    const float* __restrict__ Wq, const float* __restrict__ T,
    const float* __restrict__ u,  const float* __restrict__ bk,
    const float* __restrict__ bq, const float* __restrict__ wh,
    float* __restrict__ corr)
{
    __shared__ float As[BK][LDT64];
    __shared__ float Bs[BK][LDT64];

    const int b  = blockIdx.z;
    const int m0 = blockIdx.y * 64;
    const int n0 = blockIdx.x * 64;
    const float* Tb = T + (long)b * C_ * C_;

    const int t   = threadIdx.x;
    const int tx  = t & 15, ty = t >> 4;
    const int tx4 = tx * 4, ty4 = ty * 4;
    const int am  = t >> 2, ak4 = (t & 3) * 4;
    const int xk  = ty,     xn4 = tx4;

    float acc[4][4] = {};
    for (int k0 = 0; k0 < C_; k0 += BK) {
        float4 av = *reinterpret_cast<const float4*>(&Wq[(long)(m0 + am) * C_ + k0 + ak4]);
        float4 xv = *reinterpret_cast<const float4*>(&Tb[(long)(k0 + xk) * C_ + n0 + xn4]);
        As[ak4+0][am]=av.x; As[ak4+1][am]=av.y; As[ak4+2][am]=av.z; As[ak4+3][am]=av.w;
        *reinterpret_cast<float4*>(&Bs[xk][xn4]) = xv;
        __syncthreads();
        #pragma unroll
        for (int kk = 0; kk < BK; ++kk) {
            float4 a = *reinterpret_cast<const float4*>(&As[kk][ty4]);
            float4 x = *reinterpret_cast<const float4*>(&Bs[kk][tx4]);
            const float ar[4] = {a.x,a.y,a.z,a.w};
            const float xr[4] = {x.x,x.y,x.z,x.w};
            #pragma unroll
            for (int r = 0; r < 4; ++r)
                #pragma unroll
                for (int s = 0; s < 4; ++s)
                    acc[r][s] = fmaf(ar[r], xr[s], acc[r][s]);
        }
        __syncthreads();
    }

    float4 bkv = *reinterpret_cast<const float4*>(&bk[n0 + tx4]);
    float4 whv = *reinterpret_cast<const float4*>(&wh[b * C_ + n0 + tx4]);
    float* Yb = corr + (long)b * C_ * C_;
    #pragma unroll
    for (int r = 0; r < 4; ++r) {
        const int m = m0 + ty4 + r;
        const float um = u[b * C_ + m];
        const float bm = bq[m];
        float4 o;
        o.x = acc[r][0] + um*bkv.x + bm*whv.x;
        o.y = acc[r][1] + um*bkv.y + bm*whv.y;
        o.z = acc[r][2] + um*bkv.z + bm*whv.z;
        o.w = acc[r][3] + um*bkv.w + bm*whv.w;
        *reinterpret_cast<float4*>(&Yb[(long)m * C_ + n0 + tx4]) = o;
    }
}

// ===========================================================================
// softmax stats per row: stats[row] = max, stats[2048+row] = sum(exp(x-max))
// ===========================================================================
__global__ __launch_bounds__(256) void softmax_stats(
    const float* __restrict__ S, float* __restrict__ stats)
{
    const int row = blockIdx.x;
    const float* sr = S + (long)row * HW_;
    const int t = threadIdx.x;

    float4 x[4];
    #pragma unroll
    for (int j = 0; j < 4; ++j)
        x[j] = *reinterpret_cast<const float4*>(&sr[(j * 256 + t) * 4]);

    float m = -INFINITY;
    #pragma unroll
    for (int j = 0; j < 4; ++j)
        m = fmaxf(m, fmaxf(fmaxf(x[j].x, x[j].y), fmaxf(x[j].z, x[j].w)));
    __shared__ float red[8];
    #pragma unroll
    for (int o = 32; o > 0; o >>= 1) m = fmaxf(m, __shfl_xor(m, o));
    const int wid = t >> 6;
    if ((t & 63) == 0) red[wid] = m;
    __syncthreads();
    m = fmaxf(fmaxf(red[0], red[1]), fmaxf(red[2], red[3]));

    float sum = 0.0f;
    #pragma unroll
    for (int j = 0; j < 4; ++j)
        sum += __expf(x[j].x - m) + __expf(x[j].y - m)
             + __expf(x[j].z - m) + __expf(x[j].w - m);
    #pragma unroll
    for (int o = 32; o > 0; o >>= 1) sum += __shfl_xor(sum, o);
    if ((t & 63) == 0) red[4 + wid] = sum;
    __syncthreads();
    if (t == 0) {
        stats[row]        = m;
        stats[2048 + row] = red[4] + red[5] + red[6] + red[7];
    }
}

// ===========================================================================
extern "C" void kernel_launch(void* const* d_in, const int* in_sizes, int n_in,
                              void* d_out, int out_size, void* d_ws, size_t ws_size,
                              hipStream_t stream)
{
    const float* fg    = (const float*)d_in[0];
    const float* bg    = (const float*)d_in[1];
    const float* mask  = (const float*)d_in[2];
    const float* Wq    = (const float*)d_in[3];
    const float* bq    = (const float*)d_in[4];
    const float* Wk    = (const float*)d_in[5];
    const float* bk    = (const float*)d_in[6];
    const float* Wv    = (const float*)d_in[7];
    const float* bv    = (const float*)d_in[8];
    const float* gamma = (const float*)d_in[9];
    float* out = (float*)d_out;

    // workspace layout (floats); scores aliases part (part dead after reduce_part)
    float* ws     = (float*)d_ws;
    float* part   = ws;                         // KS*B*C*C = 16,777,216
    float* scores = ws;                         // B*C*HW  =  8,388,608 (alias)
    float* S1     = ws + 16777216;              // 524,288
    float* T      = S1 + 524288;                // 524,288
    float* corr   = T + 524288;                 // 524,288
    float* stats  = corr + 524288;              // 4,096
    float* fsum   = stats + 4096;               // 2,048
    float* gsum   = fsum + 2048;                // 2,048
    float* u      = gsum + 2048;                // 2,048
    float* wh     = u + 2048;                   // 2,048

    const dim3 blk(256);

    // 1. row sums of fg/bg (for exact bias terms)
    rowsums<<<dim3(B_ * C_), blk, 0, stream>>>(fg, bg, fsum, gsum);

    // 2. F*G^T partials (K-split over HW), then reduce -> S1 [B,C,C]
    gemm_nt128<<<dim3(2, 2, B_ * KS), blk, 0, stream>>>(fg, bg, part);
    reduce_part<<<dim3(B_ * C_ * C_ / 256), blk, 0, stream>>>(part, S1);

    // 3. rank-1 helper vectors
    uvw_kernel<<<dim3(16), blk, 0, stream>>>(Wq, Wk, bk, fsum, gsum, u, wh);

    // 4. T = S1 * Wk^T  (M=2048,N=256,K=256)
    gemm_nt64<<<dim3(C_ / 64, B_ * C_ / 64), blk, 0, stream>>>(S1, Wk, T);

    // 5. corr = Wq * T + u*bk^T + bq*wh^T
    gemm_nn64_rank1<<<dim3(4, 4, B_), blk, 0, stream>>>(Wq, T, u, bk, bq, wh, corr);

    // 6. scores = corr * mask
    gemm_nn128<<<dim3(HW_ / 128, C_ / 128, B_), blk, 0, stream>>>(
        corr, (long)C_ * C_, mask, CHW_, scores, CHW_, HW_, C_);

    // 7. softmax stats per row
    softmax_stats<<<dim3(B_ * C_), blk, 0, stream>>>(scores, stats);

    // 8. v = Wv*fg + bv fused with final elementwise combine
    gemm_v_final128<<<dim3(HW_ / 128, C_ / 128, B_), blk, 0, stream>>>(
        Wv, fg, bv, mask, scores, stats, gamma, out);
}

// Round 3
// 293.545 us; speedup vs baseline: 1.5580x; 1.3365x over previous
//
#include <hip/hip_runtime.h>
#include <math.h>

#define B_    8
#define C_    256
#define HW_   4096
#define CHW_  ((long)C_ * HW_)

#define BKT   32      // bf16 K per tile
#define LDH   40      // LDS row stride in ushorts (80 B -> 2-way max bank alias, free)
#define KS    16      // split-K for F*G^T
#define KCH   (HW_ / KS)   // 256

typedef __attribute__((ext_vector_type(8))) short bf16x8;
typedef __attribute__((ext_vector_type(4))) float f32x4;
#define MFMA_BF16(a, b, c) __builtin_amdgcn_mfma_f32_16x16x32_bf16((a), (b), (c), 0, 0, 0)

// fp32x4 -> bf16 hi (RNE-ish) + bf16 lo (truncated residual), packed 2 bf16/dword
__device__ __forceinline__ void cvt_hl4(const float4 f, uint* h, uint* l) {
    uint u0 = __float_as_uint(f.x), u1 = __float_as_uint(f.y),
         u2 = __float_as_uint(f.z), u3 = __float_as_uint(f.w);
    uint h0 = (u0 + 0x8000u) & 0xFFFF0000u, h1 = (u1 + 0x8000u) & 0xFFFF0000u,
         h2 = (u2 + 0x8000u) & 0xFFFF0000u, h3 = (u3 + 0x8000u) & 0xFFFF0000u;
    h[0] = (h0 >> 16) | h1;
    h[1] = (h2 >> 16) | h3;
    float l0 = f.x - __uint_as_float(h0), l1 = f.y - __uint_as_float(h1),
          l2 = f.z - __uint_as_float(h2), l3 = f.w - __uint_as_float(h3);
    uint a0 = __float_as_uint(l0) & 0xFFFF0000u, a1 = __float_as_uint(l1) & 0xFFFF0000u,
         a2 = __float_as_uint(l2) & 0xFFFF0000u, a3 = __float_as_uint(l3) & 0xFFFF0000u;
    l[0] = (a0 >> 16) | a1;
    l[1] = (a2 >> 16) | a3;
}
__device__ __forceinline__ void cvt_h4(const float4 f, uint* h) {
    uint u0 = __float_as_uint(f.x), u1 = __float_as_uint(f.y),
         u2 = __float_as_uint(f.z), u3 = __float_as_uint(f.w);
    uint h0 = (u0 + 0x8000u) & 0xFFFF0000u, h1 = (u1 + 0x8000u) & 0xFFFF0000u,
         h2 = (u2 + 0x8000u) & 0xFFFF0000u, h3 = (u3 + 0x8000u) & 0xFFFF0000u;
    h[0] = (h0 >> 16) | h1;
    h[1] = (h2 >> 16) | h3;
}

// ===========================================================================
// NT MFMA GEMM (split-K): part[z][c][d] += F[b][c][i]*G[b][d][i] over i-chunk.
// fp32 inputs converted to bf16 hi/lo in registers during staging. 3-pass.
// ===========================================================================
__global__ __launch_bounds__(256, 2) void gemm_nt_mfma(
    const float* __restrict__ F, const float* __restrict__ G,
    float* __restrict__ part)
{
    __shared__ ushort Ah[128 * LDH], Al[128 * LDH], Bh[128 * LDH], Bl[128 * LDH];

    const int z  = blockIdx.z;
    const int b  = z >> 4;
    const int ks = z & (KS - 1);
    const int c0 = blockIdx.y * 128;
    const int d0 = blockIdx.x * 128;
    const float* Fb = F + (long)b * CHW_ + (long)ks * KCH;
    const float* Gb = G + (long)b * CHW_ + (long)ks * KCH;

    const int t    = threadIdx.x;
    const int srow = t >> 1;            // staging row 0..127
    const int sk   = (t & 1) * 16;      // staging k offset (bf16 units)
    const int lane = t & 63, w = t >> 6;
    const int col  = lane & 15, quad = lane >> 4;
    const int wm   = (w >> 1) * 64, wn = (w & 1) * 64;

    f32x4 acc[4][4] = {};

    for (int kt = 0; kt < KCH; kt += BKT) {
        // ---- stage A (F rows) ----
        {
            const float* s = &Fb[(long)(c0 + srow) * HW_ + kt + sk];
            uint h[4], l[4];
            cvt_hl4(*reinterpret_cast<const float4*>(s),     h + 0, l + 0);
            cvt_hl4(*reinterpret_cast<const float4*>(s + 4), h + 2, l + 2);
            *reinterpret_cast<uint4*>(&Ah[srow * LDH + sk]) = make_uint4(h[0], h[1], h[2], h[3]);
            *reinterpret_cast<uint4*>(&Al[srow * LDH + sk]) = make_uint4(l[0], l[1], l[2], l[3]);
            cvt_hl4(*reinterpret_cast<const float4*>(s + 8),  h + 0, l + 0);
            cvt_hl4(*reinterpret_cast<const float4*>(s + 12), h + 2, l + 2);
            *reinterpret_cast<uint4*>(&Ah[srow * LDH + sk + 8]) = make_uint4(h[0], h[1], h[2], h[3]);
            *reinterpret_cast<uint4*>(&Al[srow * LDH + sk + 8]) = make_uint4(l[0], l[1], l[2], l[3]);
        }
        // ---- stage B (G rows) ----
        {
            const float* s = &Gb[(long)(d0 + srow) * HW_ + kt + sk];
            uint h[4], l[4];
            cvt_hl4(*reinterpret_cast<const float4*>(s),     h + 0, l + 0);
            cvt_hl4(*reinterpret_cast<const float4*>(s + 4), h + 2, l + 2);
            *reinterpret_cast<uint4*>(&Bh[srow * LDH + sk]) = make_uint4(h[0], h[1], h[2], h[3]);
            *reinterpret_cast<uint4*>(&Bl[srow * LDH + sk]) = make_uint4(l[0], l[1], l[2], l[3]);
            cvt_hl4(*reinterpret_cast<const float4*>(s + 8),  h + 0, l + 0);
            cvt_hl4(*reinterpret_cast<const float4*>(s + 12), h + 2, l + 2);
            *reinterpret_cast<uint4*>(&Bh[srow * LDH + sk + 8]) = make_uint4(h[0], h[1], h[2], h[3]);
            *reinterpret_cast<uint4*>(&Bl[srow * LDH + sk + 8]) = make_uint4(l[0], l[1], l[2], l[3]);
        }
        __syncthreads();

        bf16x8 bfh[4], bfl[4];
        #pragma unroll
        for (int tj = 0; tj < 4; ++tj) {
            const int r = (wn + tj * 16 + col) * LDH + quad * 8;
            bfh[tj] = *reinterpret_cast<const bf16x8*>(&Bh[r]);
            bfl[tj] = *reinterpret_cast<const bf16x8*>(&Bl[r]);
        }
        #pragma unroll
        for (int ti = 0; ti < 4; ++ti) {
            const int r = (wm + ti * 16 + col) * LDH + quad * 8;
            bf16x8 afh = *reinterpret_cast<const bf16x8*>(&Ah[r]);
            bf16x8 afl = *reinterpret_cast<const bf16x8*>(&Al[r]);
            #pragma unroll
            for (int tj = 0; tj < 4; ++tj) {
                acc[ti][tj] = MFMA_BF16(afh, bfh[tj], acc[ti][tj]);
                acc[ti][tj] = MFMA_BF16(afh, bfl[tj], acc[ti][tj]);
                acc[ti][tj] = MFMA_BF16(afl, bfh[tj], acc[ti][tj]);
            }
        }
        __syncthreads();
    }

    float* P = part + (long)z * C_ * C_;
    #pragma unroll
    for (int ti = 0; ti < 4; ++ti) {
        const int m = c0 + wm + ti * 16 + quad * 4;
        #pragma unroll
        for (int tj = 0; tj < 4; ++tj) {
            const int n = d0 + wn + tj * 16 + col;
            #pragma unroll
            for (int r = 0; r < 4; ++r)
                P[(long)(m + r) * C_ + n] = acc[ti][tj][r];
        }
    }
}

// ===========================================================================
// scores = corr * mask  via MFMA 3-pass.  A=corr fp32 (cvt in-reg, [c][e]),
// B = maskT hi/lo bf16 ([i][e], pre-transposed). Output scores fp32 [c][i].
// ===========================================================================
__global__ __launch_bounds__(256, 2) void gemm_scores_mfma(
    const float* __restrict__ corr,
    const ushort* __restrict__ mTh, const ushort* __restrict__ mTl,
    float* __restrict__ S)
{
    __shared__ ushort Ah[128 * LDH], Al[128 * LDH], Bh[128 * LDH], Bl[128 * LDH];

    const int b  = blockIdx.z;
    const int m0 = blockIdx.y * 128;         // c
    const int n0 = blockIdx.x * 128;         // i
    const float*  Ab  = corr + (long)b * C_ * C_;
    const ushort* Bhb = mTh + (long)b * CHW_;
    const ushort* Blb = mTl + (long)b * CHW_;

    const int t    = threadIdx.x;
    const int srow = t >> 1;
    const int sk   = (t & 1) * 16;
    const int lane = t & 63, w = t >> 6;
    const int col  = lane & 15, quad = lane >> 4;
    const int wm   = (w >> 1) * 64, wn = (w & 1) * 64;

    f32x4 acc[4][4] = {};

    for (int kt = 0; kt < C_; kt += BKT) {
        {   // stage A (corr fp32 -> hi/lo)
            const float* s = &Ab[(long)(m0 + srow) * C_ + kt + sk];
            uint h[4], l[4];
            cvt_hl4(*reinterpret_cast<const float4*>(s),     h + 0, l + 0);
            cvt_hl4(*reinterpret_cast<const float4*>(s + 4), h + 2, l + 2);
            *reinterpret_cast<uint4*>(&Ah[srow * LDH + sk]) = make_uint4(h[0], h[1], h[2], h[3]);
            *reinterpret_cast<uint4*>(&Al[srow * LDH + sk]) = make_uint4(l[0], l[1], l[2], l[3]);
            cvt_hl4(*reinterpret_cast<const float4*>(s + 8),  h + 0, l + 0);
            cvt_hl4(*reinterpret_cast<const float4*>(s + 12), h + 2, l + 2);
            *reinterpret_cast<uint4*>(&Ah[srow * LDH + sk + 8]) = make_uint4(h[0], h[1], h[2], h[3]);
            *reinterpret_cast<uint4*>(&Al[srow * LDH + sk + 8]) = make_uint4(l[0], l[1], l[2], l[3]);
        }
        {   // stage B (maskT bf16, direct copy)
            const long o = (long)(n0 + srow) * C_ + kt + sk;
            uint4 v0 = *reinterpret_cast<const uint4*>(&Bhb[o]);
            uint4 v1 = *reinterpret_cast<const uint4*>(&Bhb[o + 8]);
            uint4 w0 = *reinterpret_cast<const uint4*>(&Blb[o]);
            uint4 w1 = *reinterpret_cast<const uint4*>(&Blb[o + 8]);
            *reinterpret_cast<uint4*>(&Bh[srow * LDH + sk])     = v0;
            *reinterpret_cast<uint4*>(&Bh[srow * LDH + sk + 8]) = v1;
            *reinterpret_cast<uint4*>(&Bl[srow * LDH + sk])     = w0;
            *reinterpret_cast<uint4*>(&Bl[srow * LDH + sk + 8]) = w1;
        }
        __syncthreads();

        bf16x8 bfh[4], bfl[4];
        #pragma unroll
        for (int tj = 0; tj < 4; ++tj) {
            const int r = (wn + tj * 16 + col) * LDH + quad * 8;
            bfh[tj] = *reinterpret_cast<const bf16x8*>(&Bh[r]);
            bfl[tj] = *reinterpret_cast<const bf16x8*>(&Bl[r]);
        }
        #pragma unroll
        for (int ti = 0; ti < 4; ++ti) {
            const int r = (wm + ti * 16 + col) * LDH + quad * 8;
            bf16x8 afh = *reinterpret_cast<const bf16x8*>(&Ah[r]);
            bf16x8 afl = *reinterpret_cast<const bf16x8*>(&Al[r]);
            #pragma unroll
            for (int tj = 0; tj < 4; ++tj) {
                acc[ti][tj] = MFMA_BF16(afh, bfh[tj], acc[ti][tj]);
                acc[ti][tj] = MFMA_BF16(afh, bfl[tj], acc[ti][tj]);
                acc[ti][tj] = MFMA_BF16(afl, bfh[tj], acc[ti][tj]);
            }
        }
        __syncthreads();
    }

    float* Sb = S + (long)b * CHW_;
    #pragma unroll
    for (int ti = 0; ti < 4; ++ti) {
        const int m = m0 + wm + ti * 16 + quad * 4;
        #pragma unroll
        for (int tj = 0; tj < 4; ++tj) {
            const int n = n0 + wn + tj * 16 + col;
            #pragma unroll
            for (int r = 0; r < 4; ++r)
                Sb[(long)(m + r) * HW_ + n] = acc[ti][tj][r];
        }
    }
}

// ===========================================================================
// v = Wv*fg + bv (single-pass bf16 MFMA) fused with finalize epilogue.
// A = Wv fp32 (cvt hi in-reg, [c][e]); B = fgT hi bf16 ([i][e]).
// ===========================================================================
__global__ __launch_bounds__(256, 2) void gemm_v_final_mfma(
    const float* __restrict__ Wv, const ushort* __restrict__ fTh,
    const float* __restrict__ bv, const float* __restrict__ fg,
    const float* __restrict__ mask, const float* __restrict__ S,
    const float* __restrict__ stats, const float* __restrict__ gamma,
    float* __restrict__ out)
{
    __shared__ ushort Ahh[128 * LDH], Bhh[128 * LDH];

    const int b  = blockIdx.z;
    const int m0 = blockIdx.y * 128;        // c
    const int n0 = blockIdx.x * 128;        // i
    const ushort* Bb = fTh + (long)b * CHW_;

    const int t    = threadIdx.x;
    const int srow = t >> 1;
    const int sk   = (t & 1) * 16;
    const int lane = t & 63, w = t >> 6;
    const int col  = lane & 15, quad = lane >> 4;
    const int wm   = (w >> 1) * 64, wn = (w & 1) * 64;

    f32x4 acc[4][4] = {};

    for (int kt = 0; kt < C_; kt += BKT) {
        {   // stage A (Wv fp32 -> hi bf16)
            const float* s = &Wv[(long)(m0 + srow) * C_ + kt + sk];
            uint h[4];
            cvt_h4(*reinterpret_cast<const float4*>(s),     h + 0);
            cvt_h4(*reinterpret_cast<const float4*>(s + 4), h + 2);
            *reinterpret_cast<uint4*>(&Ahh[srow * LDH + sk]) = make_uint4(h[0], h[1], h[2], h[3]);
            cvt_h4(*reinterpret_cast<const float4*>(s + 8),  h + 0);
            cvt_h4(*reinterpret_cast<const float4*>(s + 12), h + 2);
            *reinterpret_cast<uint4*>(&Ahh[srow * LDH + sk + 8]) = make_uint4(h[0], h[1], h[2], h[3]);
        }
        {   // stage B (fgT hi bf16 direct)
            const long o = (long)(n0 + srow) * C_ + kt + sk;
            uint4 v0 = *reinterpret_cast<const uint4*>(&Bb[o]);
            uint4 v1 = *reinterpret_cast<const uint4*>(&Bb[o + 8]);
            *reinterpret_cast<uint4*>(&Bhh[srow * LDH + sk])     = v0;
            *reinterpret_cast<uint4*>(&Bhh[srow * LDH + sk + 8]) = v1;
        }
        __syncthreads();

        bf16x8 bfh[4];
        #pragma unroll
        for (int tj = 0; tj < 4; ++tj)
            bfh[tj] = *reinterpret_cast<const bf16x8*>(&Bhh[(wn + tj * 16 + col) * LDH + quad * 8]);
        #pragma unroll
        for (int ti = 0; ti < 4; ++ti) {
            bf16x8 afh = *reinterpret_cast<const bf16x8*>(&Ahh[(wm + ti * 16 + col) * LDH + quad * 8]);
            #pragma unroll
            for (int tj = 0; tj < 4; ++tj)
                acc[ti][tj] = MFMA_BF16(afh, bfh[tj], acc[ti][tj]);
        }
        __syncthreads();
    }

    const float g = gamma[0];
    #pragma unroll
    for (int ti = 0; ti < 4; ++ti) {
        const int m = m0 + wm + ti * 16 + quad * 4;
        #pragma unroll
        for (int r = 0; r < 4; ++r) {
            const int row  = b * C_ + m + r;
            const float mx  = stats[row];
            const float inv = 1.0f / stats[B_ * C_ + row];
            const float bvm = bv[m + r];
            #pragma unroll
            for (int tj = 0; tj < 4; ++tj) {
                const int n = n0 + wn + tj * 16 + col;
                const long e = (long)b * CHW_ + (long)(m + r) * HW_ + n;
                const float f  = fg[e];
                const float mk = mask[e];
                const float sv = S[e];
                const float vv = acc[ti][tj][r] + bvm;
                out[e] = f * mk + g * (1.0f - mk) * (__expf(sv - mx) * inv) * vv;
            }
        }
    }
}

// ===========================================================================
// Transposed bf16 conversion: mask[b][e][i] -> maskT hi/lo [b][i][e];
// fg -> fgT hi [b][i][e].   64x64 tiles through LDS.
// ===========================================================================
__global__ __launch_bounds__(256) void conv_transpose(
    const float* __restrict__ mask, const float* __restrict__ fg,
    ushort* __restrict__ mTh, ushort* __restrict__ mTl, ushort* __restrict__ fTh)
{
    __shared__ float tile[64][65];
    const int zi = blockIdx.z;
    const bool domask = zi < B_;
    const int b = domask ? zi : zi - B_;
    const float* src = (domask ? mask : fg) + (long)b * CHW_;
    const int e0 = blockIdx.y * 64, i0 = blockIdx.x * 64;

    const int t  = threadIdx.x;
    const int tr = t >> 4, tc = (t & 15) * 4;

    #pragma unroll
    for (int j = 0; j < 4; ++j) {
        const int e = tr + j * 16;
        float4 v = *reinterpret_cast<const float4*>(&src[(long)(e0 + e) * HW_ + i0 + tc]);
        tile[e][tc + 0] = v.x; tile[e][tc + 1] = v.y;
        tile[e][tc + 2] = v.z; tile[e][tc + 3] = v.w;
    }
    __syncthreads();

    #pragma unroll
    for (int j = 0; j < 4; ++j) {
        const int i = tr + j * 16;
        float4 v = make_float4(tile[tc + 0][i], tile[tc + 1][i], tile[tc + 2][i], tile[tc + 3][i]);
        const long o = (long)b * CHW_ + (long)(i0 + i) * C_ + e0 + tc;
        if (domask) {
            uint h[2], l[2];
            cvt_hl4(v, h, l);
            *reinterpret_cast<uint2*>(&mTh[o]) = make_uint2(h[0], h[1]);
            *reinterpret_cast<uint2*>(&mTl[o]) = make_uint2(l[0], l[1]);
        } else {
            uint h[2];
            cvt_h4(v, h);
            *reinterpret_cast<uint2*>(&fTh[o]) = make_uint2(h[0], h[1]);
        }
    }
}

// ===========================================================================
// rowsums, reduce, rank-1 helpers, small fp32 GEMMs, softmax stats (unchanged)
// ===========================================================================
__global__ __launch_bounds__(256) void rowsums(
    const float* __restrict__ fg, const float* __restrict__ bg,
    float* __restrict__ fsum, float* __restrict__ gsum)
{
    const int row = blockIdx.x;
    const int t   = threadIdx.x;
    const float* fr = fg + (long)row * HW_;
    const float* gr = bg + (long)row * HW_;
    float sf = 0.0f, sg = 0.0f;
    #pragma unroll
    for (int j = 0; j < 4; ++j) {
        float4 a = *reinterpret_cast<const float4*>(&fr[(j * 256 + t) * 4]);
        float4 c = *reinterpret_cast<const float4*>(&gr[(j * 256 + t) * 4]);
        sf += a.x + a.y + a.z + a.w;
        sg += c.x + c.y + c.z + c.w;
    }
    #pragma unroll
    for (int o = 32; o > 0; o >>= 1) { sf += __shfl_xor(sf, o); sg += __shfl_xor(sg, o); }
    __shared__ float red[8];
    const int wid = t >> 6;
    if ((t & 63) == 0) { red[wid] = sf; red[4 + wid] = sg; }
    __syncthreads();
    if (t == 0) {
        fsum[row] = red[0] + red[1] + red[2] + red[3];
        gsum[row] = red[4] + red[5] + red[6] + red[7];
    }
}

__global__ __launch_bounds__(256) void reduce_part(
    const float* __restrict__ part, float* __restrict__ S1)
{
    const long idx = (long)blockIdx.x * 256 + threadIdx.x;   // B*C*C
    const int  b   = (int)(idx >> 16);
    const long e   = idx & 65535;
    const float* p = part + ((long)b * KS) * 65536 + e;
    float s = 0.0f;
    #pragma unroll
    for (int ks = 0; ks < KS; ++ks) s += p[(long)ks * 65536];
    S1[idx] = s;
}

__global__ __launch_bounds__(256) void uvw_kernel(
    const float* __restrict__ Wq, const float* __restrict__ Wk,
    const float* __restrict__ bk,
    const float* __restrict__ fsum, const float* __restrict__ gsum,
    float* __restrict__ u, float* __restrict__ wh)
{
    const int g = blockIdx.x * 256 + threadIdx.x;
    if (g < 2048) {
        const int b = g >> 8, c = g & 255;
        const float* w = Wq + (long)c * C_;
        const float* s = fsum + b * C_;
        float acc = 0.0f;
        for (int e = 0; e < C_; ++e) acc = fmaf(w[e], s[e], acc);
        u[g] = acc;
    } else {
        const int g2 = g - 2048;
        const int b = g2 >> 8, d = g2 & 255;
        const float* w = Wk + (long)d * C_;
        const float* s = gsum + b * C_;
        float acc = 0.0f;
        for (int f = 0; f < C_; ++f) acc = fmaf(w[f], s[f], acc);
        wh[g2] = acc + (float)HW_ * bk[d];
    }
}

#define BK64 16
#define LDT64 68
__global__ __launch_bounds__(256) void gemm_nt64(
    const float* __restrict__ S1, const float* __restrict__ Wk,
    float* __restrict__ T)
{
    __shared__ float As[BK64][LDT64];
    __shared__ float Bs[BK64][LDT64];
    const int r0 = blockIdx.y * 64;
    const int d0 = blockIdx.x * 64;
    const int t   = threadIdx.x;
    const int tx  = t & 15, ty = t >> 4;
    const int tx4 = tx * 4, ty4 = ty * 4;
    const int am  = t >> 2, ak4 = (t & 3) * 4;

    float acc[4][4] = {};
    for (int k0 = 0; k0 < C_; k0 += BK64) {
        float4 av = *reinterpret_cast<const float4*>(&S1[(long)(r0 + am) * C_ + k0 + ak4]);
        float4 bw = *reinterpret_cast<const float4*>(&Wk[(long)(d0 + am) * C_ + k0 + ak4]);
        As[ak4+0][am]=av.x; As[ak4+1][am]=av.y; As[ak4+2][am]=av.z; As[ak4+3][am]=av.w;
        Bs[ak4+0][am]=bw.x; Bs[ak4+1][am]=bw.y; Bs[ak4+2][am]=bw.z; Bs[ak4+3][am]=bw.w;
        __syncthreads();
        #pragma unroll
        for (int kk = 0; kk < BK64; ++kk) {
            float4 a = *reinterpret_cast<const float4*>(&As[kk][ty4]);
            float4 x = *reinterpret_cast<const float4*>(&Bs[kk][tx4]);
            const float ar[4] = {a.x,a.y,a.z,a.w};
            const float xr[4] = {x.x,x.y,x.z,x.w};
            #pragma unroll
            for (int r = 0; r < 4; ++r)
                #pragma unroll
                for (int s = 0; s < 4; ++s)
                    acc[r][s] = fmaf(ar[r], xr[s], acc[r][s]);
        }
        __syncthreads();
    }
    #pragma unroll
    for (int r = 0; r < 4; ++r) {
        float4 o; o.x=acc[r][0]; o.y=acc[r][1]; o.z=acc[r][2]; o.w=acc[r][3];
        *reinterpret_cast<float4*>(&T[(long)(r0 + ty4 + r) * C_ + d0 + tx4]) = o;
    }
}

__global__ __launch_bounds__(256) void gemm_nn64_rank1(
    const float* __restrict__ Wq, const float* __restrict__ T,
    const float* __restrict__ u,  const float* __restrict__ bk,
    const float* __restrict__ bq, const float* __restrict__ wh,
    float* __restrict__ corr)
{
    __shared__ float As[BK64][LDT64];
    __shared__ float Bs[BK64][LDT64];
    const int b  = blockIdx.z;
    const int m0 = blockIdx.y * 64;
    const int n0 = blockIdx.x * 64;
    const float* Tb = T + (long)b * C_ * C_;

    const int t   = threadIdx.x;
    const int tx  = t & 15, ty = t >> 4;
    const int tx4 = tx * 4, ty4 = ty * 4;
    const int am  = t >> 2, ak4 = (t & 3) * 4;
    const int xk  = ty,     xn4 = tx4;

    float acc[4][4] = {};
    for (int k0 = 0; k0 < C_; k0 += BK64) {
        float4 av = *reinterpret_cast<const float4*>(&Wq[(long)(m0 + am) * C_ + k0 + ak4]);
        float4 xv = *reinterpret_cast<const float4*>(&Tb[(long)(k0 + xk) * C_ + n0 + xn4]);
        As[ak4+0][am]=av.x; As[ak4+1][am]=av.y; As[ak4+2][am]=av.z; As[ak4+3][am]=av.w;
        *reinterpret_cast<float4*>(&Bs[xk][xn4]) = xv;
        __syncthreads();
        #pragma unroll
        for (int kk = 0; kk < BK64; ++kk) {
            float4 a = *reinterpret_cast<const float4*>(&As[kk][ty4]);
            float4 x = *reinterpret_cast<const float4*>(&Bs[kk][tx4]);
            const float ar[4] = {a.x,a.y,a.z,a.w};
            const float xr[4] = {x.x,x.y,x.z,x.w};
            #pragma unroll
            for (int r = 0; r < 4; ++r)
                #pragma unroll
                for (int s = 0; s < 4; ++s)
                    acc[r][s] = fmaf(ar[r], xr[s], acc[r][s]);
        }
        __syncthreads();
    }

    float4 bkv = *reinterpret_cast<const float4*>(&bk[n0 + tx4]);
    float4 whv = *reinterpret_cast<const float4*>(&wh[b * C_ + n0 + tx4]);
    float* Yb = corr + (long)b * C_ * C_;
    #pragma unroll
    for (int r = 0; r < 4; ++r) {
        const int m = m0 + ty4 + r;
        const float um = u[b * C_ + m];
        const float bm = bq[m];
        float4 o;
        o.x = acc[r][0] + um*bkv.x + bm*whv.x;
        o.y = acc[r][1] + um*bkv.y + bm*whv.y;
        o.z = acc[r][2] + um*bkv.z + bm*whv.z;
        o.w = acc[r][3] + um*bkv.w + bm*whv.w;
        *reinterpret_cast<float4*>(&Yb[(long)m * C_ + n0 + tx4]) = o;
    }
}

__global__ __launch_bounds__(256) void softmax_stats(
    const float* __restrict__ S, float* __restrict__ stats)
{
    const int row = blockIdx.x;
    const float* sr = S + (long)row * HW_;
    const int t = threadIdx.x;
    float4 x[4];
    #pragma unroll
    for (int j = 0; j < 4; ++j)
        x[j] = *reinterpret_cast<const float4*>(&sr[(j * 256 + t) * 4]);
    float m = -INFINITY;
    #pragma unroll
    for (int j = 0; j < 4; ++j)
        m = fmaxf(m, fmaxf(fmaxf(x[j].x, x[j].y), fmaxf(x[j].z, x[j].w)));
    __shared__ float red[8];
    #pragma unroll
    for (int o = 32; o > 0; o >>= 1) m = fmaxf(m, __shfl_xor(m, o));
    const int wid = t >> 6;
    if ((t & 63) == 0) red[wid] = m;
    __syncthreads();
    m = fmaxf(fmaxf(red[0], red[1]), fmaxf(red[2], red[3]));
    float sum = 0.0f;
    #pragma unroll
    for (int j = 0; j < 4; ++j)
        sum += __expf(x[j].x - m) + __expf(x[j].y - m)
             + __expf(x[j].z - m) + __expf(x[j].w - m);
    #pragma unroll
    for (int o = 32; o > 0; o >>= 1) sum += __shfl_xor(sum, o);
    if ((t & 63) == 0) red[4 + wid] = sum;
    __syncthreads();
    if (t == 0) {
        stats[row]            = m;
        stats[B_ * C_ + row]  = red[4] + red[5] + red[6] + red[7];
    }
}

// ===========================================================================
extern "C" void kernel_launch(void* const* d_in, const int* in_sizes, int n_in,
                              void* d_out, int out_size, void* d_ws, size_t ws_size,
                              hipStream_t stream)
{
    const float* fg    = (const float*)d_in[0];
    const float* bg    = (const float*)d_in[1];
    const float* mask  = (const float*)d_in[2];
    const float* Wq    = (const float*)d_in[3];
    const float* bq    = (const float*)d_in[4];
    const float* Wk    = (const float*)d_in[5];
    const float* bk    = (const float*)d_in[6];
    const float* Wv    = (const float*)d_in[7];
    const float* bv    = (const float*)d_in[8];
    const float* gamma = (const float*)d_in[9];
    float* out = (float*)d_out;

    // ---- workspace layout (bytes) ----
    char* ws = (char*)d_ws;
    float*  part   = (float*)(ws);                       // KS*B*C*C fp32 = 33,554,432 B
    float*  scores = (float*)(ws);                       // B*C*HW fp32 (aliases part)
    ushort* mTh    = (ushort*)(ws + 33554432);           // 16,777,216 B
    ushort* mTl    = (ushort*)(ws + 50331648);           // 16,777,216 B
    ushort* fTh    = (ushort*)(ws + 67108864);           // 16,777,216 B
    float*  S1     = (float*)(ws + 83886080);            // 2,097,152 B
    float*  T      = (float*)(ws + 85983232);            // 2,097,152 B
    float*  corr   = (float*)(ws + 88080384);            // 2,097,152 B
    float*  stats  = (float*)(ws + 90177536);            // 16,384 B
    float*  fsum   = (float*)(ws + 90193920);
    float*  gsum   = (float*)(ws + 90202112);
    float*  u      = (float*)(ws + 90210304);
    float*  wh     = (float*)(ws + 90218496);

    const dim3 blk(256);

    // 1. row sums (exact bias terms)
    rowsums<<<dim3(B_ * C_), blk, 0, stream>>>(fg, bg, fsum, gsum);

    // 2. transposed bf16 conversions: mask -> maskT h/l, fg -> fgT h
    conv_transpose<<<dim3(HW_ / 64, C_ / 64, 2 * B_), blk, 0, stream>>>(
        mask, fg, mTh, mTl, fTh);

    // 3. S1 = F*G^T via split-K MFMA, then reduce
    gemm_nt_mfma<<<dim3(2, 2, B_ * KS), blk, 0, stream>>>(fg, bg, part);
    reduce_part<<<dim3(B_ * C_ * C_ / 256), blk, 0, stream>>>(part, S1);

    // 4. rank-1 helper vectors
    uvw_kernel<<<dim3(16), blk, 0, stream>>>(Wq, Wk, bk, fsum, gsum, u, wh);

    // 5. T = S1 * Wk^T ; corr = Wq*T + u*bk^T + bq*wh^T   (small fp32)
    gemm_nt64<<<dim3(C_ / 64, B_ * C_ / 64), blk, 0, stream>>>(S1, Wk, T);
    gemm_nn64_rank1<<<dim3(4, 4, B_), blk, 0, stream>>>(Wq, T, u, bk, bq, wh, corr);

    // 6. scores = corr * mask (MFMA 3-pass)
    gemm_scores_mfma<<<dim3(HW_ / 128, C_ / 128, B_), blk, 0, stream>>>(
        corr, mTh, mTl, scores);

    // 7. softmax stats
    softmax_stats<<<dim3(B_ * C_), blk, 0, stream>>>(scores, stats);

    // 8. v-GEMM (single bf16) + fused finalize
    gemm_v_final_mfma<<<dim3(HW_ / 128, C_ / 128, B_), blk, 0, stream>>>(
        Wv, fTh, bv, fg, mask, scores, stats, gamma, out);
}